// Round 10
// baseline (436.245 us; speedup 1.0000x reference)
//
#include <hip/hip_runtime.h>
#include <hip/hip_bf16.h>
#include <hip/hip_fp16.h>

#define TABN   4096
#define ROWS   (TABN + 1)           // table rows per interaction
#define DMAX   6.5f
#define DELTA  (DMAX / (float)TABN)
#define INVD   ((float)TABN / DMAX)
#define LOG2F_ 0.6931471805599453f
#define SBITS  9                    // 512 tgt-nodes per bucket
#define TILE   2048                 // edges per stage tile

__device__ __forceinline__ float ssp(float x) {
    // shifted softplus via fast-math intrinsics: log(1+e^x) - log(2)
    return fmaxf(x, 0.f) + __logf(1.f + __expf(-fabsf(x))) - LOG2F_;
}

// ---------------- filter lookup table: W_i(d) for d = t*DELTA ----------------
__global__ void ftab_kernel(const float* __restrict__ fw1, const float* __restrict__ fb1,
                            const float* __restrict__ fw2, const float* __restrict__ fb2,
                            float* __restrict__ ftab) {
    int t = blockIdx.x;          // 0..ROWS-1
    int i = blockIdx.y;          // interaction 0/1
    int j = threadIdx.x;         // 0..63 channel
    float d = (float)t * DELTA;
    float acc = fb1[i * 64 + j];
    for (int k = 0; k < 51; ++k) {
        float u = d - 0.1f * (float)k;
        float r = __expf(-10.f * u * u);
        acc = fmaf(r, fw1[((size_t)i * 51 + k) * 64 + j], acc);
    }
    __shared__ float h[64];
    h[j] = ssp(acc);
    __syncthreads();
    float o = fb2[i * 64 + j];
    for (int k = 0; k < 64; ++k)
        o = fmaf(h[k], fw2[((size_t)i * 64 + k) * 64 + j], o);
    ftab[((size_t)i * ROWS + t) * 64 + j] = o;
}

// ------- pack lerp endpoints: fpair[i][t][c] = (W[t][c], W[t+1][c]) ----------
__global__ void fpack_kernel(const float* __restrict__ ftab, float2* __restrict__ fpair) {
    int t = blockIdx.x, i = blockIdx.y, j = threadIdx.x;
    const float* r = ftab + ((size_t)i * ROWS + t) * 64;
    fpair[((size_t)i * TABN + t) * 64 + j] = make_float2(r[j], r[j + 64]);
}

// ---------------- bucket histogram (LDS-privatized) ----------------
__global__ void bhist_kernel(const int* __restrict__ ei, int* __restrict__ bcnt, int E) {
    __shared__ int h[256];
    int tid = threadIdx.x;
    h[tid] = 0;
    __syncthreads();
    for (int e = blockIdx.x * blockDim.x + tid; e < E; e += gridDim.x * blockDim.x)
        atomicAdd(&h[ei[E + e] >> SBITS], 1);
    __syncthreads();
    if (h[tid]) atomicAdd(&bcnt[tid], h[tid]);
}

// ---------------- bucket exclusive scan (tiny, single thread) ----------------
__global__ void bscan_kernel(const int* __restrict__ bcnt, int* __restrict__ bbase,
                             int* __restrict__ bcur, int nbuck) {
    if (threadIdx.x == 0) {
        int run = 0;
        for (int b = 0; b < nbuck; ++b) { bbase[b] = run; bcur[b] = run; run += bcnt[b]; }
        bbase[nbuck] = run;
    }
}

// ------- stage: LDS multisplit of edge tiles into bucket-ordered stg ---------
// payload: w0 = src | (t&511)<<17 ; w1 = ti<<20 | frac_q20
__global__ __launch_bounds__(256, 4)
void stage_kernel(const float* __restrict__ pos, const int* __restrict__ ei,
                  int* __restrict__ bcur, int2* __restrict__ stg, int E, int nbuck) {
    __shared__ int hist[256], loff[256], gbase[256], sc[256];
    __shared__ int2 sp[TILE];
    __shared__ short sb[TILE];
    int tid = threadIdx.x;
    int tile0 = blockIdx.x * TILE;
    int cnt = min(TILE, E - tile0);
    hist[tid] = 0;
    __syncthreads();
    int myrank[8], myb[8]; int2 mypay[8];
#pragma unroll
    for (int u = 0; u < 8; ++u) {
        int i = u * 256 + tid;
        myb[u] = -1;
        if (i < cnt) {
            int e = tile0 + i;
            int s = ei[e], t = ei[E + e];
            float dx = pos[3 * s]     - pos[3 * t];
            float dy = pos[3 * s + 1] - pos[3 * t + 1];
            float dz = pos[3 * s + 2] - pos[3 * t + 2];
            float d = sqrtf(dx * dx + dy * dy + dz * dz);
            float ds = fminf(d, DMAX) * INVD;
            int ti = min((int)ds, TABN - 1);
            int frq = min((int)((ds - (float)ti) * 1048576.f), 1048575);
            mypay[u] = make_int2(s | ((t & 511) << 17), (ti << 20) | frq);
            myb[u] = t >> SBITS;
            myrank[u] = atomicAdd(&hist[myb[u]], 1);
        }
    }
    __syncthreads();
    sc[tid] = hist[tid];
    __syncthreads();
    for (int o = 1; o < 256; o <<= 1) {
        int v = (tid >= o) ? sc[tid - o] : 0;
        __syncthreads();
        sc[tid] += v;
        __syncthreads();
    }
    loff[tid] = sc[tid] - hist[tid];
    if (tid < nbuck && hist[tid] > 0) gbase[tid] = atomicAdd(&bcur[tid], hist[tid]);
    __syncthreads();
#pragma unroll
    for (int u = 0; u < 8; ++u)
        if (myb[u] >= 0) {
            int idx = loff[myb[u]] + myrank[u];
            sp[idx] = mypay[u];
            sb[idx] = (short)myb[u];
        }
    __syncthreads();
    for (int i = tid; i < cnt; i += 256) {
        int b = sb[i];
        stg[gbase[b] + (i - loff[b])] = sp[i];
    }
}

// ------- place: per bucket, exact CSR placement with LDS-only atomics --------
__global__ __launch_bounds__(256)
void place_kernel(const int2* __restrict__ stg, const int* __restrict__ bbase,
                  int* __restrict__ off, int2* __restrict__ edata, int n, int nbuck) {
    int b = blockIdx.x;
    int n0 = b << SBITS;
    int nn = min(512, n - n0);
    int q0 = bbase[b], q1 = bbase[b + 1];
    __shared__ int cnt[512], cur[512], sc[256];
    int tid = threadIdx.x;
    cnt[tid] = 0; cnt[tid + 256] = 0;
    __syncthreads();
    for (int q = q0 + tid; q < q1; q += 256)
        atomicAdd(&cnt[(stg[q].x >> 17) & 511], 1);
    __syncthreads();
    int c0 = cnt[2 * tid], c1 = cnt[2 * tid + 1];
    int s = c0 + c1;
    sc[tid] = s;
    __syncthreads();
    for (int o = 1; o < 256; o <<= 1) {
        int v = (tid >= o) ? sc[tid - o] : 0;
        __syncthreads();
        sc[tid] += v;
        __syncthreads();
    }
    int run = sc[tid] - s;        // exclusive over node pairs
    cur[2 * tid] = run;
    cur[2 * tid + 1] = run + c0;
    if (2 * tid < nn)     off[n0 + 2 * tid]     = q0 + run;
    if (2 * tid + 1 < nn) off[n0 + 2 * tid + 1] = q0 + run + c0;
    if (b == nbuck - 1 && tid == 0) off[n] = q1;
    __syncthreads();
    for (int q = q0 + tid; q < q1; q += 256) {
        int2 v = stg[q];
        int p = atomicAdd(&cur[(v.x >> 17) & 511], 1);
        edata[q0 + p] = v;
    }
}

// ---------------- x = emb_z[z] ----------------
__global__ void embed_kernel(const int* __restrict__ z, const float* __restrict__ emb,
                             float* __restrict__ x, int n) {
    int idx = blockIdx.x * blockDim.x + threadIdx.x;   // over n*16 float4 chunks
    if (idx >= n * 16) return;
    int node = idx >> 4, c = idx & 15;
    ((float4*)x)[idx] = ((const float4*)emb)[z[node] * 16 + c];
}

// ---------------- solvent head for the 4 unique solvent rows ----------------
__global__ void solv_kernel(const float* __restrict__ emb_solv,
                            const float* __restrict__ w1, const float* __restrict__ b1,
                            const float* __restrict__ w2, const float* __restrict__ b2,
                            float* __restrict__ s4) {
    __shared__ float h[4][64];
    int t = threadIdx.x, r = t >> 6, j = t & 63;
    float acc = b1[j];
    for (int k = 0; k < 64; ++k) acc = fmaf(emb_solv[r * 64 + k], w1[k * 64 + j], acc);
    h[r][j] = ssp(acc);
    __syncthreads();
    if (j < 32) {
        float a = b2[j];
        for (int k = 0; k < 64; ++k) a = fmaf(h[r][k], w2[k * 32 + j], a);
        s4[r * 32 + j] = a;
    }
}

// ------------- m = x@W+b, fp16 output (consumed only by agg) -----------------
// quarter-channel split as before; converts accumulators to __half2 on store.
__global__ __launch_bounds__(256, 4)
void mm1h_kernel(const float* __restrict__ in, const float* __restrict__ w,
                 const float* __restrict__ b, __half* __restrict__ out, int n) {
    int tid = threadIdx.x;
    int q = __builtin_amdgcn_readfirstlane(tid >> 6);   // 0..3, wave-uniform
    int node = blockIdx.x * 64 + (tid & 63);
    node = min(node, n - 1);                    // no divergent return
    const float4* in4 = (const float4*)(in + (size_t)node * 64);
    const float* wq = w + q * 16;
    const float* bq = b + q * 16;
    float acc[16];
#pragma unroll
    for (int j = 0; j < 16; ++j) acc[j] = bq[j];
#pragma unroll 2
    for (int kk = 0; kk < 16; ++kk) {
        float4 xv = in4[kk];
        const float* w0 = wq + kk * 256;
#pragma unroll
        for (int j = 0; j < 16; ++j) acc[j] = fmaf(xv.x, w0[j],       acc[j]);
#pragma unroll
        for (int j = 0; j < 16; ++j) acc[j] = fmaf(xv.y, w0[64 + j],  acc[j]);
#pragma unroll
        for (int j = 0; j < 16; ++j) acc[j] = fmaf(xv.z, w0[128 + j], acc[j]);
#pragma unroll
        for (int j = 0; j < 16; ++j) acc[j] = fmaf(xv.w, w0[192 + j], acc[j]);
    }
    __half2* o2 = (__half2*)(out + (size_t)node * 64 + q * 16);
#pragma unroll
    for (int c = 0; c < 8; ++c)
        o2[c] = __floats2half2_rn(acc[2 * c], acc[2 * c + 1]);
}

// ------- fused 2-layer: out = ssp(in@W1+b1)@W2+b2 (+ res), quarter split -----
#define HSTR 65
template <bool RES>
__global__ __launch_bounds__(256, 4)
void mm2_kernel(const float* __restrict__ in,
                const float* __restrict__ w1, const float* __restrict__ b1,
                const float* __restrict__ w2, const float* __restrict__ b2,
                const float* __restrict__ res, float* __restrict__ out, int n) {
    __shared__ float hl[64 * HSTR];
    int tid = threadIdx.x;
    int q = __builtin_amdgcn_readfirstlane(tid >> 6);   // 0..3, wave-uniform
    int nl = tid & 63;
    int node = blockIdx.x * 64 + nl;
    node = min(node, n - 1);

    const float4* in4 = (const float4*)(in + (size_t)node * 64);
    const float* w1q = w1 + q * 16;
    const float* b1q = b1 + q * 16;
    float acc[16];
#pragma unroll
    for (int j = 0; j < 16; ++j) acc[j] = b1q[j];
#pragma unroll 2
    for (int kk = 0; kk < 16; ++kk) {
        float4 xv = in4[kk];
        const float* w0 = w1q + kk * 256;
#pragma unroll
        for (int j = 0; j < 16; ++j) acc[j] = fmaf(xv.x, w0[j],       acc[j]);
#pragma unroll
        for (int j = 0; j < 16; ++j) acc[j] = fmaf(xv.y, w0[64 + j],  acc[j]);
#pragma unroll
        for (int j = 0; j < 16; ++j) acc[j] = fmaf(xv.z, w0[128 + j], acc[j]);
#pragma unroll
        for (int j = 0; j < 16; ++j) acc[j] = fmaf(xv.w, w0[192 + j], acc[j]);
    }
    float* hrow = hl + nl * HSTR + q * 16;
#pragma unroll
    for (int j = 0; j < 16; ++j) hrow[j] = ssp(acc[j]);
    __syncthreads();

    const float* hfull = hl + nl * HSTR;
    const float* w2q = w2 + q * 16;
    const float* b2q = b2 + q * 16;
    float acc2[16];
#pragma unroll
    for (int j = 0; j < 16; ++j) acc2[j] = b2q[j];
#pragma unroll 4
    for (int k = 0; k < 64; ++k) {
        float hk = hfull[k];
        const float* w0 = w2q + k * 64;
#pragma unroll
        for (int j = 0; j < 16; ++j) acc2[j] = fmaf(hk, w0[j], acc2[j]);
    }
    const float4* r4 = (const float4*)(res + (size_t)node * 64 + q * 16);
    float4* o4 = (float4*)(out + (size_t)node * 64 + q * 16);
#pragma unroll
    for (int c = 0; c < 4; ++c) {
        float4 v;
        v.x = acc2[4 * c];     v.y = acc2[4 * c + 1];
        v.z = acc2[4 * c + 2]; v.w = acc2[4 * c + 3];
        if constexpr (RES) {
            float4 rv = r4[c];
            v.x += rv.x; v.y += rv.y; v.z += rv.z; v.w += rv.w;
        }
        o4[c] = v;
    }
}

// ---------------- per-node aggregation: agg[t] = sum_e m[src]*W(d) ----------
// wave per tgt node, lane = channel; m in fp16 (128B rows), lerp endpoints
// packed as float2 (one 8B load). payload: s = w0&0x1FFFF, ti = w1>>>20,
// fr = (w1&0xFFFFF)/2^20.
__global__ void agg_kernel(const int* __restrict__ off, const int2* __restrict__ edata,
                           const __half* __restrict__ m, const float2* __restrict__ fpair,
                           float* __restrict__ agg, int n) {
    int wave = (blockIdx.x * blockDim.x + threadIdx.x) >> 6;
    int lane = threadIdx.x & 63;
    if (wave >= n) return;
    int e0 = __builtin_amdgcn_readfirstlane(off[wave]);
    int e1 = __builtin_amdgcn_readfirstlane(off[wave + 1]);
    const float FRS = 1.f / 1048576.f;
    float acc[4] = {0.f, 0.f, 0.f, 0.f};
    int e = e0;
    for (; e + 8 <= e1; e += 8) {
        float mv[8], wv[8];
#pragma unroll
        for (int u = 0; u < 8; ++u) {
            int2 pd = edata[e + u];
            int s = pd.x & 0x1FFFF;
            unsigned ti = ((unsigned)pd.y) >> 20;
            float fr = (float)(pd.y & 0xFFFFF) * FRS;
            mv[u] = __half2float(m[(size_t)s * 64 + lane]);
            float2 wpr = fpair[(size_t)ti * 64 + lane];
            wv[u] = fmaf(fr, wpr.y - wpr.x, wpr.x);
        }
#pragma unroll
        for (int u = 0; u < 8; ++u) acc[u & 3] = fmaf(mv[u], wv[u], acc[u & 3]);
    }
    for (; e + 4 <= e1; e += 4) {
        float mv[4], wv[4];
#pragma unroll
        for (int u = 0; u < 4; ++u) {
            int2 pd = edata[e + u];
            int s = pd.x & 0x1FFFF;
            unsigned ti = ((unsigned)pd.y) >> 20;
            float fr = (float)(pd.y & 0xFFFFF) * FRS;
            mv[u] = __half2float(m[(size_t)s * 64 + lane]);
            float2 wpr = fpair[(size_t)ti * 64 + lane];
            wv[u] = fmaf(fr, wpr.y - wpr.x, wpr.x);
        }
#pragma unroll
        for (int u = 0; u < 4; ++u) acc[u] = fmaf(mv[u], wv[u], acc[u]);
    }
    for (; e < e1; ++e) {
        int2 pd = edata[e];
        int s = pd.x & 0x1FFFF;
        unsigned ti = ((unsigned)pd.y) >> 20;
        float fr = (float)(pd.y & 0xFFFFF) * FRS;
        float mm = __half2float(m[(size_t)s * 64 + lane]);
        float2 wpr = fpair[(size_t)ti * 64 + lane];
        acc[0] = fmaf(mm, fmaf(fr, wpr.y - wpr.x, wpr.x), acc[0]);
    }
    agg[(size_t)wave * 64 + lane] = (acc[0] + acc[1]) + (acc[2] + acc[3]);
}

// ---------------- scatter-mean pooling via binary search (batch sorted) -----
__global__ void pool_kernel(const float* __restrict__ h, const int* __restrict__ batch,
                            float* __restrict__ pooled, int n_nodes) {
    int g = blockIdx.x, j = threadIdx.x;   // block = 64
    int lo = 0, hi = n_nodes;
    while (lo < hi) { int mid = (lo + hi) >> 1; if (batch[mid] < g) lo = mid + 1; else hi = mid; }
    int start = lo;
    int lo2 = start, hi2 = n_nodes;
    while (lo2 < hi2) { int mid = (lo2 + hi2) >> 1; if (batch[mid] < g + 1) lo2 = mid + 1; else hi2 = mid; }
    int end = lo2;
    float acc = 0.f;
    for (int r = start; r < end; ++r) acc += h[(size_t)r * 64 + j];
    float cnt = (float)(end - start);
    pooled[(size_t)g * 64 + j] = acc / fmaxf(cnt, 1.f);
}

// ---------------- final graph head: 96 -> 128 -> 32 -> 1 --------------------
__global__ void post2_kernel(const float* __restrict__ pooled, const float* __restrict__ s4,
                             const int* __restrict__ solvent,
                             const float* __restrict__ w1, const float* __restrict__ b1,
                             const float* __restrict__ w2, const float* __restrict__ b2,
                             const float* __restrict__ w3, const float* __restrict__ b3,
                             float* __restrict__ out) {
    __shared__ float in96[96];
    __shared__ float l1[128];
    __shared__ float l2[32];
    int g = blockIdx.x, t = threadIdx.x;   // block = 128
    if (t < 64)      in96[t] = pooled[(size_t)g * 64 + t];
    else if (t < 96) in96[t] = s4[solvent[g] * 32 + (t - 64)];
    __syncthreads();
    float acc = b1[t];
    for (int k = 0; k < 96; ++k) acc = fmaf(in96[k], w1[k * 128 + t], acc);
    l1[t] = ssp(acc);
    __syncthreads();
    if (t < 32) {
        float a = b2[t];
        for (int k = 0; k < 128; ++k) a = fmaf(l1[k], w2[k * 32 + t], a);
        l2[t] = ssp(a);
    }
    __syncthreads();
    if (t < 32) {
        float p = l2[t] * w3[t];
        for (int o = 16; o >= 1; o >>= 1) p += __shfl_down(p, o);
        if (t == 0) out[g] = p + b3[0];
    }
}

extern "C" void kernel_launch(void* const* d_in, const int* in_sizes, int n_in,
                              void* d_out, int out_size, void* d_ws, size_t ws_size,
                              hipStream_t stream) {
    const float* pos      = (const float*)d_in[0];
    const int*   ei       = (const int*)d_in[1];
    const int*   z        = (const int*)d_in[2];
    const int*   batch    = (const int*)d_in[3];
    const int*   solvent  = (const int*)d_in[4];
    const float* emb_z    = (const float*)d_in[5];
    const float* emb_solv = (const float*)d_in[6];
    const float* solv_w1  = (const float*)d_in[7];  const float* solv_b1 = (const float*)d_in[8];
    const float* solv_w2  = (const float*)d_in[9];  const float* solv_b2 = (const float*)d_in[10];
    const float* lin1_w   = (const float*)d_in[11]; const float* lin1_b  = (const float*)d_in[12];
    const float* mlp_w1   = (const float*)d_in[13]; const float* mlp_b1  = (const float*)d_in[14];
    const float* mlp_w2   = (const float*)d_in[15]; const float* mlp_b2  = (const float*)d_in[16];
    const float* filt_w1  = (const float*)d_in[17]; const float* filt_b1 = (const float*)d_in[18];
    const float* filt_w2  = (const float*)d_in[19]; const float* filt_b2 = (const float*)d_in[20];
    const float* post_w1  = (const float*)d_in[21]; const float* post_b1 = (const float*)d_in[22];
    const float* post_w2  = (const float*)d_in[23]; const float* post_b2 = (const float*)d_in[24];
    const float* p2w1 = (const float*)d_in[25]; const float* p2b1 = (const float*)d_in[26];
    const float* p2w2 = (const float*)d_in[27]; const float* p2b2 = (const float*)d_in[28];
    const float* p2w3 = (const float*)d_in[29]; const float* p2b3 = (const float*)d_in[30];
    float* out = (float*)d_out;

    const int N = in_sizes[2];
    const int E = in_sizes[1] / 2;
    const int G = in_sizes[4];
    const int NBUCK = (N + (1 << SBITS) - 1) >> SBITS;

    char* wp = (char*)d_ws;
    auto alloc = [&](size_t bytes) -> void* {
        void* r = (void*)wp;
        wp += (bytes + 255) & ~(size_t)255;
        return r;
    };
    int2*   stg    = (int2*)  alloc((size_t)E * 8);
    int2*   edata  = (int2*)  alloc((size_t)E * 8);
    int*    bcnt   = (int*)   alloc(256 * 4);
    int*    bbase  = (int*)   alloc(257 * 4);
    int*    bcur   = (int*)   alloc(256 * 4);
    int*    off    = (int*)   alloc((size_t)(N + 1) * 4);
    float*  ftab   = (float*) alloc((size_t)2 * ROWS * 64 * 4);
    float2* fpair  = (float2*)alloc((size_t)2 * TABN * 64 * 8);
    float*  s4     = (float*) alloc(4 * 32 * 4);
    float*  x      = (float*) alloc((size_t)N * 64 * 4);
    __half* m_h    = (__half*)alloc((size_t)N * 64 * 2);
    float*  hbuf   = (float*) alloc((size_t)N * 64 * 4);
    float*  agg    = (float*) alloc((size_t)N * 64 * 4);
    float*  pooled = (float*) alloc((size_t)G * 64 * 4);
    (void)ws_size; (void)n_in; (void)out_size;

    hipMemsetAsync(bcnt, 0, 256 * 4, stream);

    ftab_kernel<<<dim3(ROWS, 2), 64, 0, stream>>>(filt_w1, filt_b1, filt_w2, filt_b2, ftab);
    fpack_kernel<<<dim3(TABN, 2), 64, 0, stream>>>(ftab, fpair);
    bhist_kernel<<<512, 256, 0, stream>>>(ei, bcnt, E);
    bscan_kernel<<<1, 64, 0, stream>>>(bcnt, bbase, bcur, NBUCK);
    stage_kernel<<<(E + TILE - 1) / TILE, 256, 0, stream>>>(pos, ei, bcur, stg, E, NBUCK);
    place_kernel<<<NBUCK, 256, 0, stream>>>(stg, bbase, off, edata, N, NBUCK);
    embed_kernel<<<((size_t)N * 16 + 255) / 256, 256, 0, stream>>>(z, emb_z, x, N);
    solv_kernel<<<1, 256, 0, stream>>>(emb_solv, solv_w1, solv_b1, solv_w2, solv_b2, s4);

    int mmg = (N + 63) / 64;
    for (int i = 0; i < 2; ++i) {
        mm1h_kernel<<<mmg, 256, 0, stream>>>(x, lin1_w + (size_t)i * 4096,
                                             lin1_b + i * 64, m_h, N);
        agg_kernel<<<(N + 3) / 4, 256, 0, stream>>>(off, edata, m_h,
                                                    fpair + (size_t)i * TABN * 64, agg, N);
        mm2_kernel<true><<<mmg, 256, 0, stream>>>(agg, mlp_w1 + (size_t)i * 4096,
                                                  mlp_b1 + i * 64, mlp_w2 + (size_t)i * 4096,
                                                  mlp_b2 + i * 64, x, x, N);
    }
    // post MLP: h = ssp(x@pw1+b1)@pw2+b2
    mm2_kernel<false><<<mmg, 256, 0, stream>>>(x, post_w1, post_b1, post_w2, post_b2,
                                               nullptr, hbuf, N);

    pool_kernel<<<G, 64, 0, stream>>>(hbuf, batch, pooled, N);
    post2_kernel<<<G, 128, 0, stream>>>(pooled, s4, solvent, p2w1, p2b1, p2w2, p2b2,
                                        p2w3, p2b3, out);
}

// Round 11
// 392.802 us; speedup vs baseline: 1.1106x; 1.1106x over previous
//
#include <hip/hip_runtime.h>
#include <hip/hip_bf16.h>
#include <hip/hip_fp16.h>

#define TABN   4096
#define ROWS   (TABN + 1)           // table rows per interaction
#define DMAX   6.5f
#define DELTA  (DMAX / (float)TABN)
#define INVD   ((float)TABN / DMAX)
#define LOG2F_ 0.6931471805599453f
#define SBITS  9                    // 512 tgt-nodes per bucket
#define TILE   2048                 // edges per stage tile

__device__ __forceinline__ float ssp(float x) {
    // shifted softplus via fast-math intrinsics: log(1+e^x) - log(2)
    return fmaxf(x, 0.f) + __logf(1.f + __expf(-fabsf(x))) - LOG2F_;
}

// ---------------- filter lookup table: W_i(d) for d = t*DELTA ----------------
__global__ void ftab_kernel(const float* __restrict__ fw1, const float* __restrict__ fb1,
                            const float* __restrict__ fw2, const float* __restrict__ fb2,
                            float* __restrict__ ftab) {
    int t = blockIdx.x;          // 0..ROWS-1
    int i = blockIdx.y;          // interaction 0/1
    int j = threadIdx.x;         // 0..63 channel
    float d = (float)t * DELTA;
    float acc = fb1[i * 64 + j];
    for (int k = 0; k < 51; ++k) {
        float u = d - 0.1f * (float)k;
        float r = __expf(-10.f * u * u);
        acc = fmaf(r, fw1[((size_t)i * 51 + k) * 64 + j], acc);
    }
    __shared__ float h[64];
    h[j] = ssp(acc);
    __syncthreads();
    float o = fb2[i * 64 + j];
    for (int k = 0; k < 64; ++k)
        o = fmaf(h[k], fw2[((size_t)i * 64 + k) * 64 + j], o);
    ftab[((size_t)i * ROWS + t) * 64 + j] = o;
}

// ------- pack lerp endpoints as fp16 pair: 4B/entry, 1MB/interaction --------
// (R10 lesson: fp32 pairs = 4MB/interaction = exactly per-XCD L2 -> thrash)
__global__ void fpack_kernel(const float* __restrict__ ftab, __half2* __restrict__ fpair) {
    int t = blockIdx.x, i = blockIdx.y, j = threadIdx.x;
    const float* r = ftab + ((size_t)i * ROWS + t) * 64;
    fpair[((size_t)i * TABN + t) * 64 + j] = __floats2half2_rn(r[j], r[j + 64]);
}

// ---------------- bucket histogram (LDS-privatized) ----------------
__global__ void bhist_kernel(const int* __restrict__ ei, int* __restrict__ bcnt, int E) {
    __shared__ int h[256];
    int tid = threadIdx.x;
    h[tid] = 0;
    __syncthreads();
    for (int e = blockIdx.x * blockDim.x + tid; e < E; e += gridDim.x * blockDim.x)
        atomicAdd(&h[ei[E + e] >> SBITS], 1);
    __syncthreads();
    if (h[tid]) atomicAdd(&bcnt[tid], h[tid]);
}

// ---------------- bucket exclusive scan (tiny, single thread) ----------------
__global__ void bscan_kernel(const int* __restrict__ bcnt, int* __restrict__ bbase,
                             int* __restrict__ bcur, int nbuck) {
    if (threadIdx.x == 0) {
        int run = 0;
        for (int b = 0; b < nbuck; ++b) { bbase[b] = run; bcur[b] = run; run += bcnt[b]; }
        bbase[nbuck] = run;
    }
}

// ------- stage: LDS multisplit of edge tiles into bucket-ordered stg ---------
// payload: w0 = src | (t&511)<<17 ; w1 = ti<<20 | frac_q20
__global__ __launch_bounds__(256, 4)
void stage_kernel(const float* __restrict__ pos, const int* __restrict__ ei,
                  int* __restrict__ bcur, int2* __restrict__ stg, int E, int nbuck) {
    __shared__ int hist[256], loff[256], gbase[256], sc[256];
    __shared__ int2 sp[TILE];
    __shared__ short sb[TILE];
    int tid = threadIdx.x;
    int tile0 = blockIdx.x * TILE;
    int cnt = min(TILE, E - tile0);
    hist[tid] = 0;
    __syncthreads();
    int myrank[8], myb[8]; int2 mypay[8];
#pragma unroll
    for (int u = 0; u < 8; ++u) {
        int i = u * 256 + tid;
        myb[u] = -1;
        if (i < cnt) {
            int e = tile0 + i;
            int s = ei[e], t = ei[E + e];
            float dx = pos[3 * s]     - pos[3 * t];
            float dy = pos[3 * s + 1] - pos[3 * t + 1];
            float dz = pos[3 * s + 2] - pos[3 * t + 2];
            float d = sqrtf(dx * dx + dy * dy + dz * dz);
            float ds = fminf(d, DMAX) * INVD;
            int ti = min((int)ds, TABN - 1);
            int frq = min((int)((ds - (float)ti) * 1048576.f), 1048575);
            mypay[u] = make_int2(s | ((t & 511) << 17), (ti << 20) | frq);
            myb[u] = t >> SBITS;
            myrank[u] = atomicAdd(&hist[myb[u]], 1);
        }
    }
    __syncthreads();
    sc[tid] = hist[tid];
    __syncthreads();
    for (int o = 1; o < 256; o <<= 1) {
        int v = (tid >= o) ? sc[tid - o] : 0;
        __syncthreads();
        sc[tid] += v;
        __syncthreads();
    }
    loff[tid] = sc[tid] - hist[tid];
    if (tid < nbuck && hist[tid] > 0) gbase[tid] = atomicAdd(&bcur[tid], hist[tid]);
    __syncthreads();
#pragma unroll
    for (int u = 0; u < 8; ++u)
        if (myb[u] >= 0) {
            int idx = loff[myb[u]] + myrank[u];
            sp[idx] = mypay[u];
            sb[idx] = (short)myb[u];
        }
    __syncthreads();
    for (int i = tid; i < cnt; i += 256) {
        int b = sb[i];
        stg[gbase[b] + (i - loff[b])] = sp[i];
    }
}

// ------- place: per bucket, exact CSR placement with LDS-only atomics --------
__global__ __launch_bounds__(256)
void place_kernel(const int2* __restrict__ stg, const int* __restrict__ bbase,
                  int* __restrict__ off, int2* __restrict__ edata, int n, int nbuck) {
    int b = blockIdx.x;
    int n0 = b << SBITS;
    int nn = min(512, n - n0);
    int q0 = bbase[b], q1 = bbase[b + 1];
    __shared__ int cnt[512], cur[512], sc[256];
    int tid = threadIdx.x;
    cnt[tid] = 0; cnt[tid + 256] = 0;
    __syncthreads();
    for (int q = q0 + tid; q < q1; q += 256)
        atomicAdd(&cnt[(stg[q].x >> 17) & 511], 1);
    __syncthreads();
    int c0 = cnt[2 * tid], c1 = cnt[2 * tid + 1];
    int s = c0 + c1;
    sc[tid] = s;
    __syncthreads();
    for (int o = 1; o < 256; o <<= 1) {
        int v = (tid >= o) ? sc[tid - o] : 0;
        __syncthreads();
        sc[tid] += v;
        __syncthreads();
    }
    int run = sc[tid] - s;        // exclusive over node pairs
    cur[2 * tid] = run;
    cur[2 * tid + 1] = run + c0;
    if (2 * tid < nn)     off[n0 + 2 * tid]     = q0 + run;
    if (2 * tid + 1 < nn) off[n0 + 2 * tid + 1] = q0 + run + c0;
    if (b == nbuck - 1 && tid == 0) off[n] = q1;
    __syncthreads();
    for (int q = q0 + tid; q < q1; q += 256) {
        int2 v = stg[q];
        int p = atomicAdd(&cur[(v.x >> 17) & 511], 1);
        edata[q0 + p] = v;
    }
}

// ---------------- x = emb_z[z] ----------------
__global__ void embed_kernel(const int* __restrict__ z, const float* __restrict__ emb,
                             float* __restrict__ x, int n) {
    int idx = blockIdx.x * blockDim.x + threadIdx.x;   // over n*16 float4 chunks
    if (idx >= n * 16) return;
    int node = idx >> 4, c = idx & 15;
    ((float4*)x)[idx] = ((const float4*)emb)[z[node] * 16 + c];
}

// ---------------- solvent head for the 4 unique solvent rows ----------------
__global__ void solv_kernel(const float* __restrict__ emb_solv,
                            const float* __restrict__ w1, const float* __restrict__ b1,
                            const float* __restrict__ w2, const float* __restrict__ b2,
                            float* __restrict__ s4) {
    __shared__ float h[4][64];
    int t = threadIdx.x, r = t >> 6, j = t & 63;
    float acc = b1[j];
    for (int k = 0; k < 64; ++k) acc = fmaf(emb_solv[r * 64 + k], w1[k * 64 + j], acc);
    h[r][j] = ssp(acc);
    __syncthreads();
    if (j < 32) {
        float a = b2[j];
        for (int k = 0; k < 64; ++k) a = fmaf(h[r][k], w2[k * 32 + j], a);
        s4[r * 32 + j] = a;
    }
}

// ------------- m = x@W+b, fp16 output (consumed only by agg) -----------------
__global__ __launch_bounds__(256, 4)
void mm1h_kernel(const float* __restrict__ in, const float* __restrict__ w,
                 const float* __restrict__ b, __half* __restrict__ out, int n) {
    int tid = threadIdx.x;
    int q = __builtin_amdgcn_readfirstlane(tid >> 6);   // 0..3, wave-uniform
    int node = blockIdx.x * 64 + (tid & 63);
    node = min(node, n - 1);                    // no divergent return
    const float4* in4 = (const float4*)(in + (size_t)node * 64);
    const float* wq = w + q * 16;
    const float* bq = b + q * 16;
    float acc[16];
#pragma unroll
    for (int j = 0; j < 16; ++j) acc[j] = bq[j];
#pragma unroll 2
    for (int kk = 0; kk < 16; ++kk) {
        float4 xv = in4[kk];
        const float* w0 = wq + kk * 256;
#pragma unroll
        for (int j = 0; j < 16; ++j) acc[j] = fmaf(xv.x, w0[j],       acc[j]);
#pragma unroll
        for (int j = 0; j < 16; ++j) acc[j] = fmaf(xv.y, w0[64 + j],  acc[j]);
#pragma unroll
        for (int j = 0; j < 16; ++j) acc[j] = fmaf(xv.z, w0[128 + j], acc[j]);
#pragma unroll
        for (int j = 0; j < 16; ++j) acc[j] = fmaf(xv.w, w0[192 + j], acc[j]);
    }
    __half2* o2 = (__half2*)(out + (size_t)node * 64 + q * 16);
#pragma unroll
    for (int c = 0; c < 8; ++c)
        o2[c] = __floats2half2_rn(acc[2 * c], acc[2 * c + 1]);
}

// ------- fused 2-layer: out = ssp(in@W1+b1)@W2+b2 (+ res), quarter split -----
#define HSTR 65
template <bool RES>
__global__ __launch_bounds__(256, 4)
void mm2_kernel(const float* __restrict__ in,
                const float* __restrict__ w1, const float* __restrict__ b1,
                const float* __restrict__ w2, const float* __restrict__ b2,
                const float* __restrict__ res, float* __restrict__ out, int n) {
    __shared__ float hl[64 * HSTR];
    int tid = threadIdx.x;
    int q = __builtin_amdgcn_readfirstlane(tid >> 6);   // 0..3, wave-uniform
    int nl = tid & 63;
    int node = blockIdx.x * 64 + nl;
    node = min(node, n - 1);

    const float4* in4 = (const float4*)(in + (size_t)node * 64);
    const float* w1q = w1 + q * 16;
    const float* b1q = b1 + q * 16;
    float acc[16];
#pragma unroll
    for (int j = 0; j < 16; ++j) acc[j] = b1q[j];
#pragma unroll 2
    for (int kk = 0; kk < 16; ++kk) {
        float4 xv = in4[kk];
        const float* w0 = w1q + kk * 256;
#pragma unroll
        for (int j = 0; j < 16; ++j) acc[j] = fmaf(xv.x, w0[j],       acc[j]);
#pragma unroll
        for (int j = 0; j < 16; ++j) acc[j] = fmaf(xv.y, w0[64 + j],  acc[j]);
#pragma unroll
        for (int j = 0; j < 16; ++j) acc[j] = fmaf(xv.z, w0[128 + j], acc[j]);
#pragma unroll
        for (int j = 0; j < 16; ++j) acc[j] = fmaf(xv.w, w0[192 + j], acc[j]);
    }
    float* hrow = hl + nl * HSTR + q * 16;
#pragma unroll
    for (int j = 0; j < 16; ++j) hrow[j] = ssp(acc[j]);
    __syncthreads();

    const float* hfull = hl + nl * HSTR;
    const float* w2q = w2 + q * 16;
    const float* b2q = b2 + q * 16;
    float acc2[16];
#pragma unroll
    for (int j = 0; j < 16; ++j) acc2[j] = b2q[j];
#pragma unroll 4
    for (int k = 0; k < 64; ++k) {
        float hk = hfull[k];
        const float* w0 = w2q + k * 64;
#pragma unroll
        for (int j = 0; j < 16; ++j) acc2[j] = fmaf(hk, w0[j], acc2[j]);
    }
    const float4* r4 = (const float4*)(res + (size_t)node * 64 + q * 16);
    float4* o4 = (float4*)(out + (size_t)node * 64 + q * 16);
#pragma unroll
    for (int c = 0; c < 4; ++c) {
        float4 v;
        v.x = acc2[4 * c];     v.y = acc2[4 * c + 1];
        v.z = acc2[4 * c + 2]; v.w = acc2[4 * c + 3];
        if constexpr (RES) {
            float4 rv = r4[c];
            v.x += rv.x; v.y += rv.y; v.z += rv.z; v.w += rv.w;
        }
        o4[c] = v;
    }
}

// ---------------- per-node aggregation: agg[t] = sum_e m[src]*W(d) ----------
// wave per tgt node, lane = channel; m fp16 (128B rows), lerp endpoints as
// __half2 (4B load, 1MB L2-resident table). payload: s = w0&0x1FFFF,
// ti = w1>>>20, fr = (w1&0xFFFFF)/2^20.
__global__ void agg_kernel(const int* __restrict__ off, const int2* __restrict__ edata,
                           const __half* __restrict__ m, const __half2* __restrict__ fpair,
                           float* __restrict__ agg, int n) {
    int wave = (blockIdx.x * blockDim.x + threadIdx.x) >> 6;
    int lane = threadIdx.x & 63;
    if (wave >= n) return;
    int e0 = __builtin_amdgcn_readfirstlane(off[wave]);
    int e1 = __builtin_amdgcn_readfirstlane(off[wave + 1]);
    const float FRS = 1.f / 1048576.f;
    float acc[4] = {0.f, 0.f, 0.f, 0.f};
    int e = e0;
    for (; e + 8 <= e1; e += 8) {
        float mv[8], wv[8];
#pragma unroll
        for (int u = 0; u < 8; ++u) {
            int2 pd = edata[e + u];
            int s = pd.x & 0x1FFFF;
            unsigned ti = ((unsigned)pd.y) >> 20;
            float fr = (float)(pd.y & 0xFFFFF) * FRS;
            mv[u] = __half2float(m[(size_t)s * 64 + lane]);
            float2 wf = __half22float2(fpair[(size_t)ti * 64 + lane]);
            wv[u] = fmaf(fr, wf.y - wf.x, wf.x);
        }
#pragma unroll
        for (int u = 0; u < 8; ++u) acc[u & 3] = fmaf(mv[u], wv[u], acc[u & 3]);
    }
    for (; e + 4 <= e1; e += 4) {
        float mv[4], wv[4];
#pragma unroll
        for (int u = 0; u < 4; ++u) {
            int2 pd = edata[e + u];
            int s = pd.x & 0x1FFFF;
            unsigned ti = ((unsigned)pd.y) >> 20;
            float fr = (float)(pd.y & 0xFFFFF) * FRS;
            mv[u] = __half2float(m[(size_t)s * 64 + lane]);
            float2 wf = __half22float2(fpair[(size_t)ti * 64 + lane]);
            wv[u] = fmaf(fr, wf.y - wf.x, wf.x);
        }
#pragma unroll
        for (int u = 0; u < 4; ++u) acc[u] = fmaf(mv[u], wv[u], acc[u]);
    }
    for (; e < e1; ++e) {
        int2 pd = edata[e];
        int s = pd.x & 0x1FFFF;
        unsigned ti = ((unsigned)pd.y) >> 20;
        float fr = (float)(pd.y & 0xFFFFF) * FRS;
        float mm = __half2float(m[(size_t)s * 64 + lane]);
        float2 wf = __half22float2(fpair[(size_t)ti * 64 + lane]);
        acc[0] = fmaf(mm, fmaf(fr, wf.y - wf.x, wf.x), acc[0]);
    }
    agg[(size_t)wave * 64 + lane] = (acc[0] + acc[1]) + (acc[2] + acc[3]);
}

// ---------------- scatter-mean pooling via binary search (batch sorted) -----
__global__ void pool_kernel(const float* __restrict__ h, const int* __restrict__ batch,
                            float* __restrict__ pooled, int n_nodes) {
    int g = blockIdx.x, j = threadIdx.x;   // block = 64
    int lo = 0, hi = n_nodes;
    while (lo < hi) { int mid = (lo + hi) >> 1; if (batch[mid] < g) lo = mid + 1; else hi = mid; }
    int start = lo;
    int lo2 = start, hi2 = n_nodes;
    while (lo2 < hi2) { int mid = (lo2 + hi2) >> 1; if (batch[mid] < g + 1) lo2 = mid + 1; else hi2 = mid; }
    int end = lo2;
    float acc = 0.f;
    for (int r = start; r < end; ++r) acc += h[(size_t)r * 64 + j];
    float cnt = (float)(end - start);
    pooled[(size_t)g * 64 + j] = acc / fmaxf(cnt, 1.f);
}

// ---------------- final graph head: 96 -> 128 -> 32 -> 1 --------------------
__global__ void post2_kernel(const float* __restrict__ pooled, const float* __restrict__ s4,
                             const int* __restrict__ solvent,
                             const float* __restrict__ w1, const float* __restrict__ b1,
                             const float* __restrict__ w2, const float* __restrict__ b2,
                             const float* __restrict__ w3, const float* __restrict__ b3,
                             float* __restrict__ out) {
    __shared__ float in96[96];
    __shared__ float l1[128];
    __shared__ float l2[32];
    int g = blockIdx.x, t = threadIdx.x;   // block = 128
    if (t < 64)      in96[t] = pooled[(size_t)g * 64 + t];
    else if (t < 96) in96[t] = s4[solvent[g] * 32 + (t - 64)];
    __syncthreads();
    float acc = b1[t];
    for (int k = 0; k < 96; ++k) acc = fmaf(in96[k], w1[k * 128 + t], acc);
    l1[t] = ssp(acc);
    __syncthreads();
    if (t < 32) {
        float a = b2[t];
        for (int k = 0; k < 128; ++k) a = fmaf(l1[k], w2[k * 32 + t], a);
        l2[t] = ssp(a);
    }
    __syncthreads();
    if (t < 32) {
        float p = l2[t] * w3[t];
        for (int o = 16; o >= 1; o >>= 1) p += __shfl_down(p, o);
        if (t == 0) out[g] = p + b3[0];
    }
}

extern "C" void kernel_launch(void* const* d_in, const int* in_sizes, int n_in,
                              void* d_out, int out_size, void* d_ws, size_t ws_size,
                              hipStream_t stream) {
    const float* pos      = (const float*)d_in[0];
    const int*   ei       = (const int*)d_in[1];
    const int*   z        = (const int*)d_in[2];
    const int*   batch    = (const int*)d_in[3];
    const int*   solvent  = (const int*)d_in[4];
    const float* emb_z    = (const float*)d_in[5];
    const float* emb_solv = (const float*)d_in[6];
    const float* solv_w1  = (const float*)d_in[7];  const float* solv_b1 = (const float*)d_in[8];
    const float* solv_w2  = (const float*)d_in[9];  const float* solv_b2 = (const float*)d_in[10];
    const float* lin1_w   = (const float*)d_in[11]; const float* lin1_b  = (const float*)d_in[12];
    const float* mlp_w1   = (const float*)d_in[13]; const float* mlp_b1  = (const float*)d_in[14];
    const float* mlp_w2   = (const float*)d_in[15]; const float* mlp_b2  = (const float*)d_in[16];
    const float* filt_w1  = (const float*)d_in[17]; const float* filt_b1 = (const float*)d_in[18];
    const float* filt_w2  = (const float*)d_in[19]; const float* filt_b2 = (const float*)d_in[20];
    const float* post_w1  = (const float*)d_in[21]; const float* post_b1 = (const float*)d_in[22];
    const float* post_w2  = (const float*)d_in[23]; const float* post_b2 = (const float*)d_in[24];
    const float* p2w1 = (const float*)d_in[25]; const float* p2b1 = (const float*)d_in[26];
    const float* p2w2 = (const float*)d_in[27]; const float* p2b2 = (const float*)d_in[28];
    const float* p2w3 = (const float*)d_in[29]; const float* p2b3 = (const float*)d_in[30];
    float* out = (float*)d_out;

    const int N = in_sizes[2];
    const int E = in_sizes[1] / 2;
    const int G = in_sizes[4];
    const int NBUCK = (N + (1 << SBITS) - 1) >> SBITS;

    char* wp = (char*)d_ws;
    auto alloc = [&](size_t bytes) -> void* {
        void* r = (void*)wp;
        wp += (bytes + 255) & ~(size_t)255;
        return r;
    };
    int2*    stg    = (int2*)   alloc((size_t)E * 8);
    int2*    edata  = (int2*)   alloc((size_t)E * 8);
    int*     bcnt   = (int*)    alloc(256 * 4);
    int*     bbase  = (int*)    alloc(257 * 4);
    int*     bcur   = (int*)    alloc(256 * 4);
    int*     off    = (int*)    alloc((size_t)(N + 1) * 4);
    float*   ftab   = (float*)  alloc((size_t)2 * ROWS * 64 * 4);
    __half2* fpair  = (__half2*)alloc((size_t)2 * TABN * 64 * 4);
    float*   s4     = (float*)  alloc(4 * 32 * 4);
    float*   x      = (float*)  alloc((size_t)N * 64 * 4);
    __half*  m_h    = (__half*) alloc((size_t)N * 64 * 2);
    float*   hbuf   = (float*)  alloc((size_t)N * 64 * 4);
    float*   agg    = (float*)  alloc((size_t)N * 64 * 4);
    float*   pooled = (float*)  alloc((size_t)G * 64 * 4);
    (void)ws_size; (void)n_in; (void)out_size;

    hipMemsetAsync(bcnt, 0, 256 * 4, stream);

    ftab_kernel<<<dim3(ROWS, 2), 64, 0, stream>>>(filt_w1, filt_b1, filt_w2, filt_b2, ftab);
    fpack_kernel<<<dim3(TABN, 2), 64, 0, stream>>>(ftab, fpair);
    bhist_kernel<<<512, 256, 0, stream>>>(ei, bcnt, E);
    bscan_kernel<<<1, 64, 0, stream>>>(bcnt, bbase, bcur, NBUCK);
    stage_kernel<<<(E + TILE - 1) / TILE, 256, 0, stream>>>(pos, ei, bcur, stg, E, NBUCK);
    place_kernel<<<NBUCK, 256, 0, stream>>>(stg, bbase, off, edata, N, NBUCK);
    embed_kernel<<<((size_t)N * 16 + 255) / 256, 256, 0, stream>>>(z, emb_z, x, N);
    solv_kernel<<<1, 256, 0, stream>>>(emb_solv, solv_w1, solv_b1, solv_w2, solv_b2, s4);

    int mmg = (N + 63) / 64;
    for (int i = 0; i < 2; ++i) {
        mm1h_kernel<<<mmg, 256, 0, stream>>>(x, lin1_w + (size_t)i * 4096,
                                             lin1_b + i * 64, m_h, N);
        agg_kernel<<<(N + 3) / 4, 256, 0, stream>>>(off, edata, m_h,
                                                    fpair + (size_t)i * TABN * 64, agg, N);
        mm2_kernel<true><<<mmg, 256, 0, stream>>>(agg, mlp_w1 + (size_t)i * 4096,
                                                  mlp_b1 + i * 64, mlp_w2 + (size_t)i * 4096,
                                                  mlp_b2 + i * 64, x, x, N);
    }
    // post MLP: h = ssp(x@pw1+b1)@pw2+b2
    mm2_kernel<false><<<mmg, 256, 0, stream>>>(x, post_w1, post_b1, post_w2, post_b2,
                                               nullptr, hbuf, N);

    pool_kernel<<<G, 64, 0, stream>>>(hbuf, batch, pooled, N);
    post2_kernel<<<G, 128, 0, stream>>>(pooled, s4, solvent, p2w1, p2b1, p2w2, p2b2,
                                        p2w3, p2b3, out);
}